// Round 8
// baseline (223.180 us; speedup 1.0000x reference)
//
#include <hip/hip_runtime.h>

#define N_NODES 8192
#define D 256
#define B 8
#define MAXDEG 128

typedef __attribute__((ext_vector_type(8))) short bf16x8;
typedef __attribute__((ext_vector_type(4))) float f32x4;
typedef __attribute__((ext_vector_type(4))) unsigned int u32x4;

// ---------- bf16 helpers ----------
static __device__ __forceinline__ float bflo(unsigned int u) {       // low bf16 of a packed u32
    union { float f; unsigned int i; } v; v.i = u << 16; return v.f;
}
static __device__ __forceinline__ float bfhi(unsigned int u) {       // high bf16 of a packed u32
    union { float f; unsigned int i; } v; v.i = u & 0xFFFF0000u; return v.f;
}
static __device__ __forceinline__ unsigned int f2bf(float f) {
    union { float f; unsigned int i; } v; v.f = f;
    unsigned int r = v.i + 0x7FFFu + ((v.i >> 16) & 1u);   // round-nearest-even
    return r >> 16;
}

// ---------- K1: dedup edges -> CSR (deg + adjacency lists) ----------
__global__ __launch_bounds__(256) void build_csr(const int* __restrict__ edges,
        unsigned int* __restrict__ bitmask, int* __restrict__ deg,
        int* __restrict__ adj, int n_edges) {
    int i = blockIdx.x * 256 + threadIdx.x;
    if (i >= n_edges) return;
    int src = edges[2 * i];
    int dst = edges[2 * i + 1];
    unsigned int bitpos = (unsigned int)src * N_NODES + (unsigned int)dst;
    unsigned int bit = 1u << (bitpos & 31u);
    unsigned int old = atomicOr(&bitmask[bitpos >> 5], bit);
    if (!(old & bit)) {                 // first time this (src,dst) is seen
        int slot = atomicAdd(&deg[src], 1);
        if (slot < MAXDEG) adj[src * MAXDEG + slot] = dst;
    }
}

// ---------- K2a: W (fp32 [k][n]) -> Wt (bf16 [n][k]) ----------
__global__ __launch_bounds__(256) void convert_wt(const float* __restrict__ W,
        unsigned short* __restrict__ Wt) {
    int idx = blockIdx.x * 256 + threadIdx.x;     // 65536 total
    int n = idx >> 8, k = idx & 255;
    Wt[n * 256 + k] = (unsigned short)f2bf(W[k * 256 + n]);
}

// ---------- K2b: x (fp32) -> xb (bf16), linear, memory-bound ----------
__global__ __launch_bounds__(256) void convert_x(const float* __restrict__ x,
        unsigned short* __restrict__ xb) {
    size_t i = ((size_t)blockIdx.x * 256 + threadIdx.x) * 8;   // 8 floats/thread
    float4 v0 = *(const float4*)(x + i);
    float4 v1 = *(const float4*)(x + i + 4);
    u32x4 o;
    o.x = f2bf(v0.x) | (f2bf(v0.y) << 16);
    o.y = f2bf(v0.z) | (f2bf(v0.w) << 16);
    o.z = f2bf(v1.x) | (f2bf(v1.y) << 16);
    o.w = f2bf(v1.z) | (f2bf(v1.w) << 16);
    *(u32x4*)(xb + i) = o;
}

// ---------- K2c: xWb = xb @ Wt^T via MFMA, all staging via global_load_lds ----------
// M=65536, K=256, N=256. Block: 128 rows x 256 cols, 512 thr (8 waves 2x4),
// wave tile 64x64, mfma_f32_16x16x32_bf16 swapped-operand (D cols = m, rows = n).
#define GBM 128
__global__ __launch_bounds__(512) void gemm_mfma(const unsigned short* __restrict__ xb,
        const unsigned short* __restrict__ Wt, unsigned short* __restrict__ xWb) {
    __shared__ alignas(16) char AsB[128 * 128];       // 128 rows x 64 bf16 (swizzled)
    __shared__ alignas(16) char WsB[256 * 128];       // 256 rows x 64 bf16 (swizzled)
    const int t = threadIdx.x;
    const int l = t & 63;
    const int w = t >> 6;
    const int wr = w >> 2;          // 0..1  (m-quadrant)
    const int wc = w & 3;           // 0..3  (n-quadrant)
    const size_t m0 = (size_t)blockIdx.x * GBM;

    f32x4 acc[4][4];
#pragma unroll
    for (int i = 0; i < 4; ++i)
#pragma unroll
        for (int j = 0; j < 4; ++j) acc[i][j] = (f32x4){0.f, 0.f, 0.f, 0.f};

    for (int ks = 0; ks < 4; ++ks) {
        const int k0 = ks * 64;
        // ---- stage A: xb bf16, global_load_lds 16B, swizzle folded into source ----
#pragma unroll
        for (int p = 0; p < 2; ++p) {
            const int row = p * 64 + w * 8 + (l >> 3);
            const int sg = (l & 7) ^ (row & 7);    // pre-swizzled source granule
            const unsigned short* gp = xb + (m0 + row) * 256 + k0 + sg * 8;
            char* lp = &AsB[p * 8192 + w * 1024];  // wave-uniform; HW adds lane*16
            __builtin_amdgcn_global_load_lds(
                (__attribute__((address_space(1))) unsigned int*)gp,
                (__attribute__((address_space(3))) unsigned int*)lp, 16, 0, 0);
        }
        // ---- stage W: same scheme, 4 issues ----
#pragma unroll
        for (int p = 0; p < 4; ++p) {
            const int rp = p * 64 + w * 8 + (l >> 3);
            const int sg = (l & 7) ^ (rp & 7);
            const unsigned short* gp = Wt + rp * 256 + k0 + sg * 8;
            char* lp = &WsB[p * 8192 + w * 1024];
            __builtin_amdgcn_global_load_lds(
                (__attribute__((address_space(1))) unsigned int*)gp,
                (__attribute__((address_space(3))) unsigned int*)lp, 16, 0, 0);
        }
        __syncthreads();
        // ---- compute: 2 k-chunks x 16 MFMA ----
#pragma unroll
        for (int kc = 0; kc < 2; ++kc) {
            bf16x8 xa[4], wb[4];
#pragma unroll
            for (int fm = 0; fm < 4; ++fm) {
                const int row = wr * 64 + fm * 16 + (l & 15);
                const int g = kc * 4 + (l >> 4);
                xa[fm] = *(const bf16x8*)&AsB[row * 128 + ((g ^ (row & 7)) * 16)];
            }
#pragma unroll
            for (int fn = 0; fn < 4; ++fn) {
                const int n = wc * 64 + fn * 16 + (l & 15);
                const int g = kc * 4 + (l >> 4);
                wb[fn] = *(const bf16x8*)&WsB[n * 128 + ((g ^ (n & 7)) * 16)];
            }
#pragma unroll
            for (int fm = 0; fm < 4; ++fm)
#pragma unroll
                for (int fn = 0; fn < 4; ++fn)
                    acc[fm][fn] = __builtin_amdgcn_mfma_f32_16x16x32_bf16(
                        wb[fn], xa[fm], acc[fm][fn], 0, 0, 0);
        }
        __syncthreads();
    }
    // ---- epilogue: lane holds 4 consecutive n -> packed 8B stores ----
#pragma unroll
    for (int fm = 0; fm < 4; ++fm) {
        const size_t m = m0 + wr * 64 + fm * 16 + (l & 15);
        unsigned short* rowp = xWb + m * 256 + wc * 64 + (l >> 4) * 4;
#pragma unroll
        for (int fn = 0; fn < 4; ++fn) {
            f32x4 v = acc[fm][fn];
            uint2 pk;
            pk.x = f2bf(v.x) | (f2bf(v.y) << 16);
            pk.y = f2bf(v.z) | (f2bf(v.w) << 16);
            *(uint2*)(rowp + fn * 16) = pk;
        }
    }
}

// ---------- K3: gather + LeakyReLU + LayerNorm, XCD-pinned per batch ----------
// block = (batch = bid&7, 8 nodes), 512 thr = 8 waves, wave = one (node,batch).
// Half-wave scheme: each half gathers parity-interleaved neighbors (2/load-instr).
// Uniform slab base -> saddr-form loads; 32-bit offset add only.
__global__ __launch_bounds__(512) void gather_ln(const unsigned short* __restrict__ xWb,
        const int* __restrict__ deg, const int* __restrict__ adj,
        const float* __restrict__ gamma, const float* __restrict__ beta,
        float* __restrict__ out) {
    const int bid = blockIdx.x;
    const int batch = bid & 7;
    const int w = threadIdx.x >> 6;
    const int l = threadIdx.x & 63;
    const int half = l >> 5;
    const int sl = l & 31;
    const int n = (bid >> 3) * 8 + w;

    __shared__ int off[8][2][64];      // [wave][parity][j] pre-shifted byte offsets
    int dg = deg[n];
    dg = dg > MAXDEG ? MAXDEG : dg;
    for (int i = l; i < dg; i += 64)
        off[w][i & 1][i >> 1] = adj[n * MAXDEG + i] << 9;   // * 512 B/row
    __syncthreads();

    const char* slab = (const char*)xWb + (size_t)batch * (N_NODES * D * 2); // uniform
    const int sl16 = sl * 16;
    const int jn = (dg - half + 1) >> 1;           // this half's neighbor count
    f32x4 a0 = {0.f, 0.f, 0.f, 0.f}, a1 = {0.f, 0.f, 0.f, 0.f};
#pragma unroll 4
    for (int j = 0; j < jn; ++j) {
        u32x4 v = *(const u32x4*)(slab + (unsigned)(off[w][half][j] + sl16));
        f32x4 c0, c1;
        c0.x = bflo(v.x); c0.y = bfhi(v.x); c0.z = bflo(v.y); c0.w = bfhi(v.y);
        c1.x = bflo(v.z); c1.y = bfhi(v.z); c1.z = bflo(v.w); c1.w = bfhi(v.w);
        a0 += c0;                       // vector adds -> v_pk_add_f32
        a1 += c1;
    }
    // combine half-wave partial sums (lanes l and l^32 cover same 8 cols)
    a0.x += __shfl_xor(a0.x, 32); a0.y += __shfl_xor(a0.y, 32);
    a0.z += __shfl_xor(a0.z, 32); a0.w += __shfl_xor(a0.w, 32);
    a1.x += __shfl_xor(a1.x, 32); a1.y += __shfl_xor(a1.y, 32);
    a1.z += __shfl_xor(a1.z, 32); a1.w += __shfl_xor(a1.w, 32);
    // LeakyReLU(0.1)
    a0.x = a0.x >= 0.f ? a0.x : 0.1f * a0.x;
    a0.y = a0.y >= 0.f ? a0.y : 0.1f * a0.y;
    a0.z = a0.z >= 0.f ? a0.z : 0.1f * a0.z;
    a0.w = a0.w >= 0.f ? a0.w : 0.1f * a0.w;
    a1.x = a1.x >= 0.f ? a1.x : 0.1f * a1.x;
    a1.y = a1.y >= 0.f ? a1.y : 0.1f * a1.y;
    a1.z = a1.z >= 0.f ? a1.z : 0.1f * a1.z;
    a1.w = a1.w >= 0.f ? a1.w : 0.1f * a1.w;
    // LayerNorm stats: 8 values/lane, butterfly over the 32-lane group
    float s = (a0.x + a0.y + a0.z + a0.w) + (a1.x + a1.y + a1.z + a1.w);
    float q = (a0.x * a0.x + a0.y * a0.y + a0.z * a0.z + a0.w * a0.w)
            + (a1.x * a1.x + a1.y * a1.y + a1.z * a1.z + a1.w * a1.w);
#pragma unroll
    for (int o = 1; o < 32; o <<= 1) {
        s += __shfl_xor(s, o);
        q += __shfl_xor(q, o);
    }
    const float mean = s * (1.f / D);
    const float var  = q * (1.f / D) - mean * mean;
    const float rstd = rsqrtf(var + 1e-5f);
    // each lane stores 4 cols: half0 -> sl*8, half1 -> sl*8+4
    f32x4 sel = half ? a1 : a0;
    const int col = sl * 8 + half * 4;
    float4 g  = *(const float4*)(gamma + col);
    float4 bt = *(const float4*)(beta + col);
    f32x4 o4;
    o4.x = g.x * (sel.x - mean) * rstd + bt.x;
    o4.y = g.y * (sel.y - mean) * rstd + bt.y;
    o4.z = g.z * (sel.z - mean) * rstd + bt.z;
    o4.w = g.w * (sel.w - mean) * rstd + bt.w;
    __builtin_nontemporal_store(o4,
        (f32x4*)(out + ((size_t)batch * N_NODES + n) * D + col));
}

// ---------- launch ----------
extern "C" void kernel_launch(void* const* d_in, const int* in_sizes, int n_in,
                              void* d_out, int out_size, void* d_ws, size_t ws_size,
                              hipStream_t stream) {
    const float* x     = (const float*)d_in[0];
    const float* W     = (const float*)d_in[1];
    const float* gamma = (const float*)d_in[2];
    const float* beta  = (const float*)d_in[3];
    const int*   edges = (const int*)d_in[4];
    const int n_edges  = in_sizes[4] / 2;

    char* ws = (char*)d_ws;
    int*            degp    = (int*)ws;                                    // 32 KB
    unsigned int*   bitmask = (unsigned int*)(ws + 32768);                 // 8 MB
    int*            adj     = (int*)(ws + 32768 + 8388608);                // 4 MB
    unsigned short* xWb     = (unsigned short*)(ws + 32768 + 8388608 + 4194304); // 32 MB
    // Wt aliases the bitmask region: written only AFTER build_csr is done
    unsigned short* Wt      = (unsigned short*)(ws + 32768);               // 128 KB
    // xb (bf16 of x, 32 MB) lives in d_out: consumed by gemm_mfma BEFORE
    // gather_ln overwrites d_out with the final output (stream-ordered).
    unsigned short* xb      = (unsigned short*)d_out;

    (void)hipMemsetAsync(d_ws, 0, 32768 + 8388608, stream);   // zero deg + bitmask

    build_csr<<<(n_edges + 255) / 256, 256, 0, stream>>>(edges, bitmask, degp, adj, n_edges);
    convert_wt<<<256, 256, 0, stream>>>(W, Wt);          // after build_csr (aliases bitmask)
    convert_x<<<8192, 256, 0, stream>>>(x, xb);
    gemm_mfma<<<(B * N_NODES) / GBM, 512, 0, stream>>>(xb, Wt, xWb);
    gather_ln<<<N_NODES, 512, 0, stream>>>(xWb, degp, adj, gamma, beta, (float*)d_out);
}